// Round 1
// baseline (200.233 us; speedup 1.0000x reference)
//
#include <hip/hip_runtime.h>

#define ALPHA 0.2f
#define MLP_ALPHA 0.01f
#define LN_EPS 1e-5f

constexpr int Bb = 4;
constexpr int Nn = 4096;
constexpr int Ff = 256;     // FIN == FOUT == 256
constexpr int Kk = 64;      // chunk size
constexpr int Cc = 64;      // N / k
constexpr int STS = 68;     // S^T row stride (pad: banks spread, 16B aligned)

// One block per (b,c) chunk. 256 threads = 4 waves; wave w owns rows
// [w*16, w*16+16); within a wave, lane covers cols lane + 64*cc, cc=0..3.
__global__ __launch_bounds__(256) void gat_fused(
    const float* __restrict__ h,   const float* __restrict__ adj,
    const float* __restrict__ W,   const float* __restrict__ a_vec,
    const float* __restrict__ g_ln, const float* __restrict__ b_ln,
    const float* __restrict__ W1,  const float* __restrict__ b1,
    const float* __restrict__ W2,  const float* __restrict__ b2,
    const float* __restrict__ W3,  const float* __restrict__ b3,
    float* __restrict__ out)
{
  __shared__ float hb[Kk * Ff];   // h chunk -> attn-out x -> y2
  __shared__ float wb[Kk * Ff];   // whc -> y1
  __shared__ float st[Kk * STS];  // S^T: st[jj*STS + i] = S[i][jj]
  __shared__ float al[Ff];        // a vector

  const int t    = threadIdx.x;
  const int lane = t & 63;
  const int wid  = t >> 6;
  const int row0 = wid * 16;
  const int bc   = blockIdx.x;
  const int b    = bc >> 6;     // / Cc
  const int c    = bc & 63;     // % Cc

  // ---------------- load h chunk + a ----------------
  {
    const float4* src = reinterpret_cast<const float4*>(h + (size_t)(b * Nn + c * Kk) * Ff);
    float4* dst = reinterpret_cast<float4*>(hb);
    #pragma unroll
    for (int it = 0; it < 16; ++it) dst[256 * it + t] = src[256 * it + t];
  }
  al[t] = a_vec[t];
  __syncthreads();   // sync1

  // prefetch this wave's adj block rows (64 contiguous floats per row)
  float adjv[16];
  #pragma unroll
  for (int rr = 0; rr < 16; ++rr)
    adjv[rr] = adj[((size_t)b * Nn + c * Kk + row0 + rr) * Nn + (c * Kk + lane)];

  // ---------------- GEMM1: whc = h_chunk @ W ----------------
  float acc[16][4];
  #pragma unroll
  for (int rr = 0; rr < 16; ++rr)
    #pragma unroll
    for (int cc = 0; cc < 4; ++cc) acc[rr][cc] = 0.f;

  for (int i = 0; i < Ff; i += 4) {
    float wv[4][4];
    #pragma unroll
    for (int u = 0; u < 4; ++u)
      #pragma unroll
      for (int cc = 0; cc < 4; ++cc)
        wv[u][cc] = W[(i + u) * Ff + lane + 64 * cc];
    #pragma unroll
    for (int rr = 0; rr < 16; ++rr) {
      const float4 hv = *reinterpret_cast<const float4*>(&hb[(row0 + rr) * Ff + i]);
      #pragma unroll
      for (int cc = 0; cc < 4; ++cc) {
        acc[rr][cc] = fmaf(hv.x, wv[0][cc], acc[rr][cc]);
        acc[rr][cc] = fmaf(hv.y, wv[1][cc], acc[rr][cc]);
        acc[rr][cc] = fmaf(hv.z, wv[2][cc], acc[rr][cc]);
        acc[rr][cc] = fmaf(hv.w, wv[3][cc], acc[rr][cc]);
      }
    }
  }
  // write whc (own rows, all cols)
  #pragma unroll
  for (int rr = 0; rr < 16; ++rr)
    #pragma unroll
    for (int cc = 0; cc < 4; ++cc)
      wb[(row0 + rr) * Ff + lane + 64 * cc] = acc[rr][cc];

  // ---------------- e + row softmax (in-register, wave-wide) ----------------
  #pragma unroll
  for (int rr = 0; rr < 16; ++rr) {
    float p = acc[rr][0] * al[lane]       + acc[rr][1] * al[lane + 64]
            + acc[rr][2] * al[lane + 128] + acc[rr][3] * al[lane + 192];
    #pragma unroll
    for (int off = 32; off; off >>= 1) p += __shfl_xor(p, off);
    const float ev = (p >= 0.f) ? p : ALPHA * p;        // e = leaky(Wh . a)
    const float x  = adjv[rr] * ev;
    float m = x;
    #pragma unroll
    for (int off = 32; off; off >>= 1) m = fmaxf(m, __shfl_xor(m, off));
    const float pe = __expf(x - m);
    float s = pe;
    #pragma unroll
    for (int off = 32; off; off >>= 1) s += __shfl_xor(s, off);
    st[lane * STS + row0 + rr] = pe / s;                // S^T[jj=lane][i]
  }
  __syncthreads();   // sync2: whc + S^T complete

  // ---------------- out = S @ whc  (wave rows, cols lane+64cc) ----------------
  {
    float o[16][4];
    #pragma unroll
    for (int rr = 0; rr < 16; ++rr)
      #pragma unroll
      for (int cc = 0; cc < 4; ++cc) o[rr][cc] = 0.f;
    for (int jj = 0; jj < Kk; ++jj) {
      float wv[4];
      #pragma unroll
      for (int cc = 0; cc < 4; ++cc) wv[cc] = wb[jj * Ff + lane + 64 * cc];
      const float4 s0 = *reinterpret_cast<const float4*>(&st[jj * STS + row0]);
      const float4 s1 = *reinterpret_cast<const float4*>(&st[jj * STS + row0 + 4]);
      const float4 s2 = *reinterpret_cast<const float4*>(&st[jj * STS + row0 + 8]);
      const float4 s3 = *reinterpret_cast<const float4*>(&st[jj * STS + row0 + 12]);
      #pragma unroll
      for (int cc = 0; cc < 4; ++cc) {
        o[0][cc]  = fmaf(s0.x, wv[cc], o[0][cc]);
        o[1][cc]  = fmaf(s0.y, wv[cc], o[1][cc]);
        o[2][cc]  = fmaf(s0.z, wv[cc], o[2][cc]);
        o[3][cc]  = fmaf(s0.w, wv[cc], o[3][cc]);
        o[4][cc]  = fmaf(s1.x, wv[cc], o[4][cc]);
        o[5][cc]  = fmaf(s1.y, wv[cc], o[5][cc]);
        o[6][cc]  = fmaf(s1.z, wv[cc], o[6][cc]);
        o[7][cc]  = fmaf(s1.w, wv[cc], o[7][cc]);
        o[8][cc]  = fmaf(s2.x, wv[cc], o[8][cc]);
        o[9][cc]  = fmaf(s2.y, wv[cc], o[9][cc]);
        o[10][cc] = fmaf(s2.z, wv[cc], o[10][cc]);
        o[11][cc] = fmaf(s2.w, wv[cc], o[11][cc]);
        o[12][cc] = fmaf(s3.x, wv[cc], o[12][cc]);
        o[13][cc] = fmaf(s3.y, wv[cc], o[13][cc]);
        o[14][cc] = fmaf(s3.z, wv[cc], o[14][cc]);
        o[15][cc] = fmaf(s3.w, wv[cc], o[15][cc]);
      }
    }
    // attn-out x into hb (h is dead)
    #pragma unroll
    for (int rr = 0; rr < 16; ++rr)
      #pragma unroll
      for (int cc = 0; cc < 4; ++cc)
        hb[(row0 + rr) * Ff + lane + 64 * cc] = o[rr][cc];
  }
  __syncthreads();   // sync3: REQUIRED (out-GEMM read all wb rows cross-wave)

  // ---------------- MLP + residual + LayerNorm ----------------
  // stash residual x (own elements) in regs so hb can be reused for y2
  float xr[16][4];
  #pragma unroll
  for (int rr = 0; rr < 16; ++rr)
    #pragma unroll
    for (int cc = 0; cc < 4; ++cc)
      xr[rr][cc] = hb[(row0 + rr) * Ff + lane + 64 * cc];

  // ---- stage 1: y1 = leaky(x @ W1 + b1) -> wb ----
  {
    float bv[4];
    #pragma unroll
    for (int cc = 0; cc < 4; ++cc) bv[cc] = b1[lane + 64 * cc];
    #pragma unroll
    for (int rr = 0; rr < 16; ++rr)
      #pragma unroll
      for (int cc = 0; cc < 4; ++cc) acc[rr][cc] = bv[cc];
    for (int i = 0; i < Ff; i += 4) {
      float wv[4][4];
      #pragma unroll
      for (int u = 0; u < 4; ++u)
        #pragma unroll
        for (int cc = 0; cc < 4; ++cc) wv[u][cc] = W1[(i + u) * Ff + lane + 64 * cc];
      #pragma unroll
      for (int rr = 0; rr < 16; ++rr) {
        const float4 xv = *reinterpret_cast<const float4*>(&hb[(row0 + rr) * Ff + i]);
        #pragma unroll
        for (int cc = 0; cc < 4; ++cc) {
          acc[rr][cc] = fmaf(xv.x, wv[0][cc], acc[rr][cc]);
          acc[rr][cc] = fmaf(xv.y, wv[1][cc], acc[rr][cc]);
          acc[rr][cc] = fmaf(xv.z, wv[2][cc], acc[rr][cc]);
          acc[rr][cc] = fmaf(xv.w, wv[3][cc], acc[rr][cc]);
        }
      }
    }
    #pragma unroll
    for (int rr = 0; rr < 16; ++rr)
      #pragma unroll
      for (int cc = 0; cc < 4; ++cc) {
        const float v = acc[rr][cc];
        wb[(row0 + rr) * Ff + lane + 64 * cc] = (v >= 0.f) ? v : MLP_ALPHA * v;
      }
  }
  // ---- stage 2: y2 = leaky(y1 @ W2 + b2) -> hb (x stashed in xr) ----
  {
    float bv[4];
    #pragma unroll
    for (int cc = 0; cc < 4; ++cc) bv[cc] = b2[lane + 64 * cc];
    #pragma unroll
    for (int rr = 0; rr < 16; ++rr)
      #pragma unroll
      for (int cc = 0; cc < 4; ++cc) acc[rr][cc] = bv[cc];
    for (int i = 0; i < Ff; i += 4) {
      float wv[4][4];
      #pragma unroll
      for (int u = 0; u < 4; ++u)
        #pragma unroll
        for (int cc = 0; cc < 4; ++cc) wv[u][cc] = W2[(i + u) * Ff + lane + 64 * cc];
      #pragma unroll
      for (int rr = 0; rr < 16; ++rr) {
        const float4 xv = *reinterpret_cast<const float4*>(&wb[(row0 + rr) * Ff + i]);
        #pragma unroll
        for (int cc = 0; cc < 4; ++cc) {
          acc[rr][cc] = fmaf(xv.x, wv[0][cc], acc[rr][cc]);
          acc[rr][cc] = fmaf(xv.y, wv[1][cc], acc[rr][cc]);
          acc[rr][cc] = fmaf(xv.z, wv[2][cc], acc[rr][cc]);
          acc[rr][cc] = fmaf(xv.w, wv[3][cc], acc[rr][cc]);
        }
      }
    }
    #pragma unroll
    for (int rr = 0; rr < 16; ++rr)
      #pragma unroll
      for (int cc = 0; cc < 4; ++cc) {
        const float v = acc[rr][cc];
        hb[(row0 + rr) * Ff + lane + 64 * cc] = (v >= 0.f) ? v : MLP_ALPHA * v;
      }
  }
  // ---- stage 3: z = y2 @ W3 + b3 + x ; LayerNorm ; store ----
  {
    float bv[4];
    #pragma unroll
    for (int cc = 0; cc < 4; ++cc) bv[cc] = b3[lane + 64 * cc];
    #pragma unroll
    for (int rr = 0; rr < 16; ++rr)
      #pragma unroll
      for (int cc = 0; cc < 4; ++cc) acc[rr][cc] = bv[cc];
    for (int i = 0; i < Ff; i += 4) {
      float wv[4][4];
      #pragma unroll
      for (int u = 0; u < 4; ++u)
        #pragma unroll
        for (int cc = 0; cc < 4; ++cc) wv[u][cc] = W3[(i + u) * Ff + lane + 64 * cc];
      #pragma unroll
      for (int rr = 0; rr < 16; ++rr) {
        const float4 xv = *reinterpret_cast<const float4*>(&hb[(row0 + rr) * Ff + i]);
        #pragma unroll
        for (int cc = 0; cc < 4; ++cc) {
          acc[rr][cc] = fmaf(xv.x, wv[0][cc], acc[rr][cc]);
          acc[rr][cc] = fmaf(xv.y, wv[1][cc], acc[rr][cc]);
          acc[rr][cc] = fmaf(xv.z, wv[2][cc], acc[rr][cc]);
          acc[rr][cc] = fmaf(xv.w, wv[3][cc], acc[rr][cc]);
        }
      }
    }
    float gv[4], lb[4];
    #pragma unroll
    for (int cc = 0; cc < 4; ++cc) { gv[cc] = g_ln[lane + 64 * cc]; lb[cc] = b_ln[lane + 64 * cc]; }
    const size_t obase = (size_t)(b * Nn + c * Kk) * Ff;
    #pragma unroll
    for (int rr = 0; rr < 16; ++rr) {
      #pragma unroll
      for (int cc = 0; cc < 4; ++cc) acc[rr][cc] += xr[rr][cc];   // residual
      float s = acc[rr][0] + acc[rr][1] + acc[rr][2] + acc[rr][3];
      float q = acc[rr][0] * acc[rr][0] + acc[rr][1] * acc[rr][1]
              + acc[rr][2] * acc[rr][2] + acc[rr][3] * acc[rr][3];
      #pragma unroll
      for (int off = 32; off; off >>= 1) { s += __shfl_xor(s, off); q += __shfl_xor(q, off); }
      const float mu  = s * (1.f / 256.f);
      const float var = q * (1.f / 256.f) - mu * mu;
      const float rs  = rsqrtf(var + LN_EPS);
      #pragma unroll
      for (int cc = 0; cc < 4; ++cc)
        out[obase + (size_t)(row0 + rr) * Ff + lane + 64 * cc] =
            (acc[rr][cc] - mu) * rs * gv[cc] + lb[cc];
    }
  }
}

extern "C" void kernel_launch(void* const* d_in, const int* in_sizes, int n_in,
                              void* d_out, int out_size, void* d_ws, size_t ws_size,
                              hipStream_t stream) {
  (void)in_sizes; (void)n_in; (void)d_ws; (void)ws_size; (void)out_size;
  gat_fused<<<dim3(Bb * Cc), dim3(256), 0, stream>>>(
      (const float*)d_in[0],  (const float*)d_in[1],  (const float*)d_in[2],
      (const float*)d_in[3],  (const float*)d_in[4],  (const float*)d_in[5],
      (const float*)d_in[6],  (const float*)d_in[7],  (const float*)d_in[8],
      (const float*)d_in[9],  (const float*)d_in[10], (const float*)d_in[11],
      (float*)d_out);
}

// Round 2
// 44.325 us; speedup vs baseline: 4.5174x; 4.5174x over previous
//
#include <hip/hip_runtime.h>

typedef __bf16 bf16;
typedef __bf16 bf16x4 __attribute__((ext_vector_type(4)));
typedef __bf16 bf16x8 __attribute__((ext_vector_type(8)));
typedef float  f32x4  __attribute__((ext_vector_type(4)));

#define ALPHA 0.2f
#define MLP_ALPHA 0.01f
#define LN_EPS 1e-5f

constexpr int Bb = 4;
constexpr int Nn = 4096;
constexpr int Ff = 256;   // FIN == FOUT
constexpr int Kk = 64;    // chunk rows
constexpr int Cc = 64;    // N / k

__device__ __forceinline__ f32x4 MFMA(bf16x8 a, bf16x8 b, f32x4 c) {
  return __builtin_amdgcn_mfma_f32_16x16x32_bf16(a, b, c, 0, 0, 0);
}
__device__ __forceinline__ bf16x4 pack4(f32x4 v) {
  bf16x4 r; r[0]=(bf16)v[0]; r[1]=(bf16)v[1]; r[2]=(bf16)v[2]; r[3]=(bf16)v[3]; return r;
}

// ---------------- prep: W,W1,W2,W3 (f32 [k][n] row-major) -> bf16 frag layout
// frag[mat][kt(8)][nt(16)][lane(64)][jj(8)] ; element = W[kt*32+(l>>4)*8+jj][nt*16+(l&15)]
// (A-frag of W^T == B-frag of W, so one gather serves GEMM1-B and MLP-A.)
__global__ __launch_bounds__(256) void prep_weights(
    const float* __restrict__ W0, const float* __restrict__ W1,
    const float* __restrict__ W2, const float* __restrict__ W3,
    bf16* __restrict__ outw)
{
  int t = blockIdx.x * 256 + threadIdx.x;     // [0, 32768)
  int l   = t & 63;
  int nt  = (t >> 6) & 15;
  int kt  = (t >> 10) & 7;
  int mat = t >> 13;
  const float* src = (mat==0) ? W0 : (mat==1) ? W1 : (mat==2) ? W2 : W3;
  int n  = nt*16 + (l & 15);
  int k0 = kt*32 + (l >> 4)*8;
  bf16x8 v;
  #pragma unroll
  for (int jj = 0; jj < 8; ++jj) v[jj] = (bf16)src[(k0 + jj)*Ff + n];
  *(bf16x8*)(outw + (size_t)t * 8) = v;
}

// MLP GEMM (transposed): acc[nt][r] += Wmat^T-frags x inBuf-frags
__device__ __forceinline__ void mlp_gemm(const bf16* __restrict__ wfrag, int mat,
                                         const bf16* inBuf, f32x4 acc[4][4],
                                         int w, int l)
{
  const int g = l >> 4, li = l & 15;
  #pragma unroll 2
  for (int kt = 0; kt < 8; ++kt) {
    bf16x8 af[4], bfr[4];
    #pragma unroll
    for (int r = 0; r < 4; ++r) {
      const bf16* p = wfrag + ((((size_t)mat*8 + kt)*16 + (w*4 + r))*64 + l)*8;
      af[r] = *(const bf16x8*)p;
    }
    #pragma unroll
    for (int nt = 0; nt < 4; ++nt) {
      int i = nt*16 + li;
      int byte = i*512 + (((kt*32 + g*8)*2) ^ ((i & 7) << 4));
      bfr[nt] = *(const bf16x8*)((const char*)inBuf + byte);
    }
    #pragma unroll
    for (int nt = 0; nt < 4; ++nt)
      #pragma unroll
      for (int r = 0; r < 4; ++r)
        acc[nt][r] = MFMA(af[r], bfr[nt], acc[nt][r]);
  }
}

// bias + leaky(0.01) + packed b64 row-major store of the transposed C-frags
__device__ __forceinline__ void stage_store(f32x4 acc[4][4], const float* __restrict__ bias,
                                            bf16* outBuf, int w, int l)
{
  const int g = l >> 4, li = l & 15;
  float bv[4][4];
  #pragma unroll
  for (int r = 0; r < 4; ++r)
    #pragma unroll
    for (int e = 0; e < 4; ++e) bv[r][e] = bias[(w*4 + r)*16 + g*4 + e];
  #pragma unroll
  for (int nt = 0; nt < 4; ++nt) {
    int i = nt*16 + li, swz = (i & 7) << 4;
    #pragma unroll
    for (int r = 0; r < 4; ++r) {
      f32x4 v;
      #pragma unroll
      for (int e = 0; e < 4; ++e) {
        float x = acc[nt][r][e] + bv[r][e];
        v[e] = (x >= 0.f) ? x : MLP_ALPHA * x;
      }
      int f0 = (w*4 + r)*16 + g*4;
      *(bf16x4*)((char*)outBuf + i*512 + ((f0*2) ^ swz)) = pack4(v);
    }
  }
}

__global__ __launch_bounds__(256, 1) void gat_mfma(
    const float* __restrict__ h,   const float* __restrict__ adj,
    const float* __restrict__ a_vec,
    const float* __restrict__ gln, const float* __restrict__ bln,
    const float* __restrict__ b1,  const float* __restrict__ b2,
    const float* __restrict__ b3,
    const bf16* __restrict__ wfrag,
    float* __restrict__ out)
{
  __shared__ bf16 bufA[Ff * Kk];   // whcT [256 f][64 j] -> y1 [64 i][256 f]
  __shared__ bf16 bufB[Kk * Ff];   // x    [64 i][256 f] -> y2
  __shared__ bf16 sS[Kk * Kk];     // S [64 i][64 j], swizzled
  __shared__ float lnS[Kk * 4], lnQ[Kk * 4];

  const int t = threadIdx.x, l = t & 63, w = t >> 6, g = l >> 4, li = l & 15;
  const int bc = blockIdx.x, b = bc >> 6, c = bc & 63;
  const size_t rbase = (size_t)b * Nn + c * Kk;

  // early adj prefetch (phase-1 mapping: wave w rows w*16+rr, lane = j)
  float adjv[16];
  #pragma unroll
  for (int rr = 0; rr < 16; ++rr)
    adjv[rr] = adj[(rbase + w*16 + rr) * Nn + (size_t)c*Kk + l];

  // ---------------- phase 0: whc = h @ W (MFMA), write whcT ----------------
  f32x4 acc1[4][4];   // [q (f col-tile within wave panel)][rt (i row-tile)]
  #pragma unroll
  for (int q = 0; q < 4; ++q)
    #pragma unroll
    for (int r = 0; r < 4; ++r) acc1[q][r] = (f32x4){0.f, 0.f, 0.f, 0.f};

  #pragma unroll 2
  for (int kt = 0; kt < 8; ++kt) {
    bf16x8 af[4];
    #pragma unroll
    for (int rt = 0; rt < 4; ++rt) {   // A: h rows rt*16+li, k-slice kt*32+g*8
      const float* hp = h + (rbase + rt*16 + li)*Ff + kt*32 + g*8;
      f32x4 h0 = *(const f32x4*)hp;
      f32x4 h1 = *(const f32x4*)(hp + 4);
      bf16x8 v;
      #pragma unroll
      for (int d = 0; d < 4; ++d) { v[d] = (bf16)h0[d]; v[4+d] = (bf16)h1[d]; }
      af[rt] = v;
    }
    #pragma unroll
    for (int q = 0; q < 4; ++q) {
      const bf16* p = wfrag + (((size_t)kt*16 + (w*4 + q))*64 + l)*8;  // mat 0
      bf16x8 bfr = *(const bf16x8*)p;
      #pragma unroll
      for (int rt = 0; rt < 4; ++rt) acc1[q][rt] = MFMA(af[rt], bfr, acc1[q][rt]);
    }
  }
  // whcT[f][j]: C-frag regs = 4 consecutive rows j -> packed b64, swz (f&7)<<4
  #pragma unroll
  for (int q = 0; q < 4; ++q) {
    int f = w*64 + q*16 + li, swz = (f & 7) << 4;
    #pragma unroll
    for (int rt = 0; rt < 4; ++rt) {
      int j0 = rt*16 + g*4;
      *(bf16x4*)((char*)bufA + f*128 + ((j0*2) ^ swz)) = pack4(acc1[q][rt]);
    }
  }
  __syncthreads();   // S0: whcT complete

  // ---------------- phase 1: e + row softmax -> S (bf16, swizzled) ----------------
  {
    float afs[4];
    #pragma unroll
    for (int q = 0; q < 4; ++q) afs[q] = a_vec[q*64 + l];
    #pragma unroll
    for (int rr = 0; rr < 16; ++rr) {
      int i = w*16 + rr;
      float p = 0.f;
      #pragma unroll
      for (int q = 0; q < 4; ++q) {      // e = leaky(sum_f whc[i][f]*a[f], 0.2)
        int f = q*64 + l;
        int byte = f*128 + ((i*2) ^ ((f & 7) << 4));
        p += (float)(*(const bf16*)((const char*)bufA + byte)) * afs[q];
      }
      #pragma unroll
      for (int off = 32; off; off >>= 1) p += __shfl_xor(p, off);
      float e = (p >= 0.f) ? p : ALPHA * p;
      float x = adjv[rr] * e;
      float m = x;
      #pragma unroll
      for (int off = 32; off; off >>= 1) m = fmaxf(m, __shfl_xor(m, off));
      float pe = __expf(x - m);
      float s = pe;
      #pragma unroll
      for (int off = 32; off; off >>= 1) s += __shfl_xor(s, off);
      float sv = pe / s;
      int byte = i*128 + ((l*2) ^ ((i & 7) << 4));
      *(bf16*)((char*)sS + byte) = (bf16)sv;
    }
  }
  __syncthreads();   // S1: S complete

  // ---------------- phase 2: xT = whcT @ ST (MFMA), write x row-major ----------------
  f32x4 xr[4][4];    // [nt (i col-tile)][r (f row-tile)] — kept as residual
  #pragma unroll
  for (int nt = 0; nt < 4; ++nt)
    #pragma unroll
    for (int r = 0; r < 4; ++r) xr[nt][r] = (f32x4){0.f, 0.f, 0.f, 0.f};
  #pragma unroll
  for (int kt = 0; kt < 2; ++kt) {
    int koff = (kt*32 + g*8) * 2;
    bf16x8 af[4], bfr[4];
    #pragma unroll
    for (int r = 0; r < 4; ++r) {       // A = whcT rows f (wave's own panel)
      int f = (w*4 + r)*16 + li;
      af[r] = *(const bf16x8*)((const char*)bufA + f*128 + (koff ^ ((f & 7) << 4)));
    }
    #pragma unroll
    for (int nt = 0; nt < 4; ++nt) {    // B = S^T via S row-major
      int i = nt*16 + li;
      bfr[nt] = *(const bf16x8*)((const char*)sS + i*128 + (koff ^ ((i & 7) << 4)));
    }
    #pragma unroll
    for (int nt = 0; nt < 4; ++nt)
      #pragma unroll
      for (int r = 0; r < 4; ++r) xr[nt][r] = MFMA(af[r], bfr[nt], xr[nt][r]);
  }
  #pragma unroll
  for (int nt = 0; nt < 4; ++nt) {      // x[i][f] packed b64
    int i = nt*16 + li, swz = (i & 7) << 4;
    #pragma unroll
    for (int r = 0; r < 4; ++r) {
      int f0 = (w*4 + r)*16 + g*4;
      *(bf16x4*)((char*)bufB + i*512 + ((f0*2) ^ swz)) = pack4(xr[nt][r]);
    }
  }
  __syncthreads();   // S2: x complete (bufA reads done)

  // ---------------- phases 3-5: MLP (transposed) ----------------
  f32x4 acc3[4][4];
  #pragma unroll
  for (int nt = 0; nt < 4; ++nt)
    #pragma unroll
    for (int r = 0; r < 4; ++r) acc3[nt][r] = (f32x4){0.f, 0.f, 0.f, 0.f};
  mlp_gemm(wfrag, 1, bufB, acc3, w, l);     // y1T = W1T @ xT
  stage_store(acc3, b1, bufA, w, l);        // y1 -> bufA
  __syncthreads();   // S3

  #pragma unroll
  for (int nt = 0; nt < 4; ++nt)
    #pragma unroll
    for (int r = 0; r < 4; ++r) acc3[nt][r] = (f32x4){0.f, 0.f, 0.f, 0.f};
  mlp_gemm(wfrag, 2, bufA, acc3, w, l);     // y2T = W2T @ y1T
  stage_store(acc3, b2, bufB, w, l);        // y2 -> bufB
  __syncthreads();   // S4

  #pragma unroll
  for (int nt = 0; nt < 4; ++nt)
    #pragma unroll
    for (int r = 0; r < 4; ++r) acc3[nt][r] = (f32x4){0.f, 0.f, 0.f, 0.f};
  mlp_gemm(wfrag, 3, bufB, acc3, w, l);     // y3T = W3T @ y2T

  // ---------------- epilogue: z = y3 + b3 + x ; LayerNorm over f ; store ----------------
  {
    float bv[4][4], gv[4][4], btv[4][4];
    #pragma unroll
    for (int r = 0; r < 4; ++r)
      #pragma unroll
      for (int e = 0; e < 4; ++e) {
        int f = (w*4 + r)*16 + g*4 + e;
        bv[r][e] = b3[f]; gv[r][e] = gln[f]; btv[r][e] = bln[f];
      }
    float ps[4], pq[4];
    #pragma unroll
    for (int nt = 0; nt < 4; ++nt) {
      float s = 0.f, qq = 0.f;
      #pragma unroll
      for (int r = 0; r < 4; ++r)
        #pragma unroll
        for (int e = 0; e < 4; ++e) {
          float z = acc3[nt][r][e] + bv[r][e] + xr[nt][r][e];
          acc3[nt][r][e] = z;
          s += z; qq += z*z;
        }
      s  += __shfl_xor(s, 16);  s  += __shfl_xor(s, 32);   // reduce over g-groups
      qq += __shfl_xor(qq, 16); qq += __shfl_xor(qq, 32);
      ps[nt] = s; pq[nt] = qq;
    }
    if (g == 0) {
      #pragma unroll
      for (int nt = 0; nt < 4; ++nt) {
        int i = nt*16 + li;
        lnS[i*4 + w] = ps[nt];
        lnQ[i*4 + w] = pq[nt];
      }
    }
    __syncthreads();   // S5: LN partials
    #pragma unroll
    for (int nt = 0; nt < 4; ++nt) {
      int i = nt*16 + li;
      f32x4 s4 = *(const f32x4*)&lnS[i*4];
      f32x4 q4 = *(const f32x4*)&lnQ[i*4];
      float s  = s4[0] + s4[1] + s4[2] + s4[3];
      float qq = q4[0] + q4[1] + q4[2] + q4[3];
      float mu  = s * (1.f/256.f);
      float var = qq * (1.f/256.f) - mu*mu;
      float rs  = rsqrtf(var + LN_EPS);
      #pragma unroll
      for (int r = 0; r < 4; ++r) {
        float4 o;
        o.x = (acc3[nt][r][0] - mu)*rs*gv[r][0] + btv[r][0];
        o.y = (acc3[nt][r][1] - mu)*rs*gv[r][1] + btv[r][1];
        o.z = (acc3[nt][r][2] - mu)*rs*gv[r][2] + btv[r][2];
        o.w = (acc3[nt][r][3] - mu)*rs*gv[r][3] + btv[r][3];
        *(float4*)&out[(rbase + i)*Ff + (w*4 + r)*16 + g*4] = o;
      }
    }
  }
}

extern "C" void kernel_launch(void* const* d_in, const int* in_sizes, int n_in,
                              void* d_out, int out_size, void* d_ws, size_t ws_size,
                              hipStream_t stream) {
  (void)in_sizes; (void)n_in; (void)out_size; (void)ws_size;
  bf16* wfrag = (bf16*)d_ws;   // 4 * 128 KB = 512 KB
  prep_weights<<<dim3(128), dim3(256), 0, stream>>>(
      (const float*)d_in[2], (const float*)d_in[6],
      (const float*)d_in[8], (const float*)d_in[10], wfrag);
  gat_mfma<<<dim3(Bb * Cc), dim3(256), 0, stream>>>(
      (const float*)d_in[0],  (const float*)d_in[1],  (const float*)d_in[3],
      (const float*)d_in[4],  (const float*)d_in[5],
      (const float*)d_in[7],  (const float*)d_in[9],  (const float*)d_in[11],
      wfrag, (float*)d_out);
}

// Round 3
// 36.821 us; speedup vs baseline: 5.4380x; 1.2038x over previous
//
#include <hip/hip_runtime.h>

typedef __bf16 bf16;
typedef __bf16 bf16x4 __attribute__((ext_vector_type(4)));
typedef __bf16 bf16x8 __attribute__((ext_vector_type(8)));
typedef float  f32x4  __attribute__((ext_vector_type(4)));

#define ALPHA 0.2f
#define MLP_ALPHA 0.01f
#define LN_EPS 1e-5f

constexpr int Bb = 4;
constexpr int Nn = 4096;
constexpr int Ff = 256;   // FIN == FOUT
constexpr int Kk = 64;    // chunk rows
constexpr int Cc = 64;    // N / k

__device__ __forceinline__ f32x4 MFMA(bf16x8 a, bf16x8 b, f32x4 c) {
  return __builtin_amdgcn_mfma_f32_16x16x32_bf16(a, b, c, 0, 0, 0);
}
__device__ __forceinline__ bf16x4 pack4(f32x4 v) {
  bf16x4 r; r[0]=(bf16)v[0]; r[1]=(bf16)v[1]; r[2]=(bf16)v[2]; r[3]=(bf16)v[3]; return r;
}
// 512B-row buffers: XOR bits 4-7 (16 slots) — avoids the g*16 collision (8-way -> 4-way)
__device__ __forceinline__ int swz512(int i, int inrow) { return i*512 + (inrow ^ ((i & 15) << 4)); }
// 128B-row buffers: XOR bits 4-6 (max for 8 slots)
__device__ __forceinline__ int swz128(int f, int inrow) { return f*128 + (inrow ^ ((f & 7) << 4)); }

// ---------------- prep: weights -> bf16 frag layout ; wa = W @ a (f32) -------
// frag[mat][kt(8)][nt(16)][lane(64)][jj(8)] ; element = W[kt*32+(l>>4)*8+jj][nt*16+(l&15)]
__global__ __launch_bounds__(256) void prep_weights(
    const float* __restrict__ W0, const float* __restrict__ W1,
    const float* __restrict__ W2, const float* __restrict__ W3,
    const float* __restrict__ a_vec,
    bf16* __restrict__ outw, float* __restrict__ wa)
{
  if (blockIdx.x == 128) {                 // wa[k] = dot(W0[k,:], a)
    int k = threadIdx.x;
    const float* row = W0 + k * Ff;
    float s = 0.f;
    for (int j = 0; j < Ff; j += 4) {
      f32x4 wv = *(const f32x4*)(row + j);
      f32x4 av = *(const f32x4*)(a_vec + j);
      s += wv[0]*av[0] + wv[1]*av[1] + wv[2]*av[2] + wv[3]*av[3];
    }
    wa[k] = s;
    return;
  }
  int t = blockIdx.x * 256 + threadIdx.x;  // [0, 32768)
  int l = t & 63, nt = (t >> 6) & 15, kt = (t >> 10) & 7, mat = t >> 13;
  const float* src = (mat==0) ? W0 : (mat==1) ? W1 : (mat==2) ? W2 : W3;
  int n  = nt*16 + (l & 15);
  int k0 = kt*32 + (l >> 4)*8;
  bf16x8 v;
  #pragma unroll
  for (int jj = 0; jj < 8; ++jj) v[jj] = (bf16)src[(k0 + jj)*Ff + n];
  *(bf16x8*)(outw + (size_t)t * 8) = v;
}

// MLP GEMM (transposed): acc[nt][r] += Wmat^T-frags x inBuf-frags  (8 waves, r<2)
__device__ __forceinline__ void mlp_gemm(const bf16* __restrict__ wfrag, int mat,
                                         const bf16* inBuf, f32x4 acc[4][2],
                                         int w, int l)
{
  const int g = l >> 4, li = l & 15;
  #pragma unroll
  for (int kt = 0; kt < 8; ++kt) {
    bf16x8 af[2], bfr[4];
    #pragma unroll
    for (int r = 0; r < 2; ++r)
      af[r] = *(const bf16x8*)(wfrag + ((((size_t)mat*8 + kt)*16 + (w*2 + r))*64 + l)*8);
    #pragma unroll
    for (int nt = 0; nt < 4; ++nt) {
      int i = nt*16 + li;
      bfr[nt] = *(const bf16x8*)((const char*)inBuf + swz512(i, (kt*32 + g*8)*2));
    }
    #pragma unroll
    for (int nt = 0; nt < 4; ++nt)
      #pragma unroll
      for (int r = 0; r < 2; ++r)
        acc[nt][r] = MFMA(af[r], bfr[nt], acc[nt][r]);
  }
}

// bias + leaky(0.01) + packed b64 row-major store of the transposed C-frags
__device__ __forceinline__ void stage_store(f32x4 acc[4][2], const float* __restrict__ bias,
                                            bf16* outBuf, int w, int l)
{
  const int g = l >> 4, li = l & 15;
  float bv[2][4];
  #pragma unroll
  for (int r = 0; r < 2; ++r)
    #pragma unroll
    for (int e = 0; e < 4; ++e) bv[r][e] = bias[(w*2 + r)*16 + g*4 + e];
  #pragma unroll
  for (int nt = 0; nt < 4; ++nt) {
    int i = nt*16 + li;
    #pragma unroll
    for (int r = 0; r < 2; ++r) {
      f32x4 v;
      #pragma unroll
      for (int e = 0; e < 4; ++e) {
        float x = acc[nt][r][e] + bv[r][e];
        v[e] = (x >= 0.f) ? x : MLP_ALPHA * x;
      }
      int f0 = (w*2 + r)*16 + g*4;
      *(bf16x4*)((char*)outBuf + swz512(i, f0*2)) = pack4(v);
    }
  }
}

__global__ __launch_bounds__(512, 2) void gat_mfma(
    const float* __restrict__ h,   const float* __restrict__ adj,
    const float* __restrict__ gln, const float* __restrict__ bln,
    const float* __restrict__ b1,  const float* __restrict__ b2,
    const float* __restrict__ b3,
    const bf16* __restrict__ wfrag, const float* __restrict__ wa,
    float* __restrict__ out)
{
  __shared__ bf16 hbs[Kk * Ff];    // h chunk, bf16, swizzled 512B rows
  __shared__ bf16 bufA[Ff * Kk];   // whcT [256 f][64 j] (128B rows) -> y1 [64 i][256 f]
  __shared__ bf16 bufB[Kk * Ff];   // x    [64 i][256 f] -> y2
  __shared__ bf16 sS[Kk * Kk];     // S [64 i][64 j], swizzled 128B rows
  __shared__ float evec[Kk];       // e[i] (pre-leaky'd)
  __shared__ float lnS[Kk * 8], lnQ[Kk * 8];

  const int t = threadIdx.x, l = t & 63, w = t >> 6, g = l >> 4, li = l & 15;
  const int bc = blockIdx.x, b = bc >> 6, c = bc & 63;
  const size_t rbase = (size_t)b * Nn + c * Kk;

  // adj prefetch: wave w rows w*8+rr, lane = j
  float adjv[8];
  #pragma unroll
  for (int rr = 0; rr < 8; ++rr)
    adjv[rr] = adj[(rbase + w*8 + rr) * Nn + (size_t)c*Kk + l];

  // ---------------- stage h -> LDS bf16 ; e[i] = leaky(h[i,:].wa) in f32 ------
  {
    const int i  = t >> 3;          // 0..63 (8 threads per row)
    const int k0 = (t & 7) * 32;
    const float* hp = h + (rbase + i) * Ff + k0;
    float p = 0.f;
    #pragma unroll
    for (int u = 0; u < 4; ++u) {
      f32x4 h0 = *(const f32x4*)(hp + u*8);
      f32x4 h1 = *(const f32x4*)(hp + u*8 + 4);
      f32x4 w0 = *(const f32x4*)(wa + k0 + u*8);
      f32x4 w1 = *(const f32x4*)(wa + k0 + u*8 + 4);
      p += h0[0]*w0[0] + h0[1]*w0[1] + h0[2]*w0[2] + h0[3]*w0[3]
         + h1[0]*w1[0] + h1[1]*w1[1] + h1[2]*w1[2] + h1[3]*w1[3];
      bf16x8 v;
      #pragma unroll
      for (int d = 0; d < 4; ++d) { v[d] = (bf16)h0[d]; v[4+d] = (bf16)h1[d]; }
      *(bf16x8*)((char*)hbs + swz512(i, (k0 + u*8)*2)) = v;
    }
    p += __shfl_xor(p, 1); p += __shfl_xor(p, 2); p += __shfl_xor(p, 4);
    if ((l & 7) == 0) evec[i] = (p >= 0.f) ? p : ALPHA * p;
  }
  __syncthreads();   // B1: hbs + evec

  // ---------------- softmax (rows w*8+rr) -> S bf16 swizzled ----------------
  #pragma unroll
  for (int rr = 0; rr < 8; ++rr) {
    int i = w*8 + rr;
    float x = adjv[rr] * evec[i];
    float m = x;
    #pragma unroll
    for (int off = 32; off; off >>= 1) m = fmaxf(m, __shfl_xor(m, off));
    float pe = __expf(x - m);
    float s = pe;
    #pragma unroll
    for (int off = 32; off; off >>= 1) s += __shfl_xor(s, off);
    *(bf16*)((char*)sS + swz128(i, l*2)) = (bf16)(pe / s);
  }

  // ---------------- phase 0: whcT = (h @ W)^T  (A from LDS) ----------------
  f32x4 acc1[2][4];   // [q: f col-tile][rt: j row-tile]
  #pragma unroll
  for (int q = 0; q < 2; ++q)
    #pragma unroll
    for (int rt = 0; rt < 4; ++rt) acc1[q][rt] = (f32x4){0.f,0.f,0.f,0.f};
  #pragma unroll
  for (int kt = 0; kt < 8; ++kt) {
    bf16x8 af[4];
    #pragma unroll
    for (int rt = 0; rt < 4; ++rt) {
      int i = rt*16 + li;
      af[rt] = *(const bf16x8*)((const char*)hbs + swz512(i, (kt*32 + g*8)*2));
    }
    #pragma unroll
    for (int q = 0; q < 2; ++q) {
      bf16x8 bfr = *(const bf16x8*)(wfrag + (((size_t)kt*16 + (w*2 + q))*64 + l)*8);
      #pragma unroll
      for (int rt = 0; rt < 4; ++rt) acc1[q][rt] = MFMA(af[rt], bfr, acc1[q][rt]);
    }
  }
  #pragma unroll
  for (int q = 0; q < 2; ++q) {
    int f = (w*2 + q)*16 + li;
    #pragma unroll
    for (int rt = 0; rt < 4; ++rt) {
      int j0 = rt*16 + g*4;
      *(bf16x4*)((char*)bufA + swz128(f, j0*2)) = pack4(acc1[q][rt]);
    }
  }
  __syncthreads();   // B2: whcT + sS complete

  // ---------------- phase 2: xT = whcT @ ST -> x row-major ----------------
  f32x4 xr[4][2];    // residual, kept in regs
  #pragma unroll
  for (int nt = 0; nt < 4; ++nt)
    #pragma unroll
    for (int r = 0; r < 2; ++r) xr[nt][r] = (f32x4){0.f,0.f,0.f,0.f};
  #pragma unroll
  for (int kt = 0; kt < 2; ++kt) {
    int koff = (kt*32 + g*8)*2;
    bf16x8 af[2], bfr[4];
    #pragma unroll
    for (int r = 0; r < 2; ++r) {
      int f = (w*2 + r)*16 + li;
      af[r] = *(const bf16x8*)((const char*)bufA + swz128(f, koff));
    }
    #pragma unroll
    for (int nt = 0; nt < 4; ++nt) {
      int i = nt*16 + li;
      bfr[nt] = *(const bf16x8*)((const char*)sS + swz128(i, koff));
    }
    #pragma unroll
    for (int nt = 0; nt < 4; ++nt)
      #pragma unroll
      for (int r = 0; r < 2; ++r) xr[nt][r] = MFMA(af[r], bfr[nt], xr[nt][r]);
  }
  #pragma unroll
  for (int nt = 0; nt < 4; ++nt) {
    int i = nt*16 + li;
    #pragma unroll
    for (int r = 0; r < 2; ++r) {
      int f0 = (w*2 + r)*16 + g*4;
      *(bf16x4*)((char*)bufB + swz512(i, f0*2)) = pack4(xr[nt][r]);
    }
  }
  __syncthreads();   // B3: x complete

  // ---------------- MLP (transposed) ----------------
  f32x4 acc3[4][2];
  #pragma unroll
  for (int nt = 0; nt < 4; ++nt)
    #pragma unroll
    for (int r = 0; r < 2; ++r) acc3[nt][r] = (f32x4){0.f,0.f,0.f,0.f};
  mlp_gemm(wfrag, 1, bufB, acc3, w, l);     // y1T = W1T @ xT
  stage_store(acc3, b1, bufA, w, l);
  __syncthreads();   // B4

  #pragma unroll
  for (int nt = 0; nt < 4; ++nt)
    #pragma unroll
    for (int r = 0; r < 2; ++r) acc3[nt][r] = (f32x4){0.f,0.f,0.f,0.f};
  mlp_gemm(wfrag, 2, bufA, acc3, w, l);     // y2T
  stage_store(acc3, b2, bufB, w, l);
  __syncthreads();   // B5

  #pragma unroll
  for (int nt = 0; nt < 4; ++nt)
    #pragma unroll
    for (int r = 0; r < 2; ++r) acc3[nt][r] = (f32x4){0.f,0.f,0.f,0.f};
  mlp_gemm(wfrag, 3, bufB, acc3, w, l);     // y3T

  // ---------------- epilogue: +b3 +x ; LayerNorm over f ; store ----------------
  {
    float bv[2][4], gv[2][4], btv[2][4];
    #pragma unroll
    for (int r = 0; r < 2; ++r)
      #pragma unroll
      for (int e = 0; e < 4; ++e) {
        int f = (w*2 + r)*16 + g*4 + e;
        bv[r][e] = b3[f]; gv[r][e] = gln[f]; btv[r][e] = bln[f];
      }
    #pragma unroll
    for (int nt = 0; nt < 4; ++nt) {
      float s = 0.f, qq = 0.f;
      #pragma unroll
      for (int r = 0; r < 2; ++r)
        #pragma unroll
        for (int e = 0; e < 4; ++e) {
          float z = acc3[nt][r][e] + bv[r][e] + xr[nt][r][e];
          acc3[nt][r][e] = z;
          s += z; qq += z*z;
        }
      s  += __shfl_xor(s, 16);  s  += __shfl_xor(s, 32);
      qq += __shfl_xor(qq, 16); qq += __shfl_xor(qq, 32);
      if (g == 0) {
        int i = nt*16 + li;
        lnS[i*8 + w] = s;
        lnQ[i*8 + w] = qq;
      }
    }
    __syncthreads();   // B6: LN partials
    #pragma unroll
    for (int nt = 0; nt < 4; ++nt) {
      int i = nt*16 + li;
      f32x4 s0 = *(const f32x4*)&lnS[i*8];
      f32x4 s1 = *(const f32x4*)&lnS[i*8 + 4];
      f32x4 q0 = *(const f32x4*)&lnQ[i*8];
      f32x4 q1 = *(const f32x4*)&lnQ[i*8 + 4];
      float s  = s0[0]+s0[1]+s0[2]+s0[3]+s1[0]+s1[1]+s1[2]+s1[3];
      float qq = q0[0]+q0[1]+q0[2]+q0[3]+q1[0]+q1[1]+q1[2]+q1[3];
      float mu  = s * (1.f/256.f);
      float var = qq * (1.f/256.f) - mu*mu;
      float rs  = rsqrtf(var + LN_EPS);
      #pragma unroll
      for (int r = 0; r < 2; ++r) {
        float4 o;
        o.x = (acc3[nt][r][0] - mu)*rs*gv[r][0] + btv[r][0];
        o.y = (acc3[nt][r][1] - mu)*rs*gv[r][1] + btv[r][1];
        o.z = (acc3[nt][r][2] - mu)*rs*gv[r][2] + btv[r][2];
        o.w = (acc3[nt][r][3] - mu)*rs*gv[r][3] + btv[r][3];
        *(float4*)&out[(rbase + i)*Ff + (w*2 + r)*16 + g*4] = o;
      }
    }
  }
}

extern "C" void kernel_launch(void* const* d_in, const int* in_sizes, int n_in,
                              void* d_out, int out_size, void* d_ws, size_t ws_size,
                              hipStream_t stream) {
  (void)in_sizes; (void)n_in; (void)out_size; (void)ws_size;
  bf16*  wfrag = (bf16*)d_ws;                       // 512 KB
  float* wa    = (float*)((char*)d_ws + 512*1024);  // 1 KB
  prep_weights<<<dim3(129), dim3(256), 0, stream>>>(
      (const float*)d_in[2], (const float*)d_in[6],
      (const float*)d_in[8], (const float*)d_in[10],
      (const float*)d_in[3], wfrag, wa);
  gat_mfma<<<dim3(Bb * Cc), dim3(512), 0, stream>>>(
      (const float*)d_in[0],  (const float*)d_in[1],
      (const float*)d_in[4],  (const float*)d_in[5],
      (const float*)d_in[7],  (const float*)d_in[9],  (const float*)d_in[11],
      wfrag, wa, (float*)d_out);
}